// Round 24
// baseline (205.389 us; speedup 1.0000x reference)
//
#include <hip/hip_runtime.h>
#include <math.h>

#define DEV __device__ __forceinline__

typedef unsigned long long u64;
typedef unsigned u32;

// monotone map: float bits -> u32 preserving < order (handles negatives)
DEV u32 fmap(float f) {
    u32 b = __float_as_uint(f);
    return b ^ (u32)(((int)b >> 31) | 0x80000000);
}
// exact inverse of fmap
DEV float funmap(u32 m) {
    u32 b = (m & 0x80000000u) ? (m ^ 0x80000000u) : ~m;
    return __uint_as_float(b);
}
DEV u32 umin_(u32 a, u32 b) { return __builtin_elementwise_min(a, b); }
DEV u32 umax_(u32 a, u32 b) { return __builtin_elementwise_max(a, b); }

// rank among lanes below me with bit set: popcll(mask & lanemask_lt), 2 VALU
DEV int lane_rank(u64 mask) {
    return (int)__builtin_amdgcn_mbcnt_hi((u32)(mask >> 32),
               __builtin_amdgcn_mbcnt_lo((u32)mask, 0u));
}

// ---- BIT-EXACT distance pieces: explicit _rn intrinsics, composed the same
// way in every kernel. R16-proven rounding (absmax 0.00390625) — do not fold.
DEV float pnorm2(float x, float y, float z) {
    return __fmaf_rn(x, x, __fmaf_rn(y, y, __fmul_rn(z, z)));
}
DEV float qdot(float qx, float qy, float qz, float px, float py, float pz) {
    return __fmaf_rn(qx, px, __fmaf_rn(qy, py, __fmul_rn(qz, pz)));
}
DEV float dist2_core(float qq, float pp, float qp) {
    return __fadd_rn(__fadd_rn(qq, pp), __fmul_rn(-2.f, qp));
}
DEV float dist2(float qx, float qy, float qz, float qq,
                float px, float py, float pz) {
    return dist2_core(qq, pnorm2(px, py, pz), qdot(qx, qy, qz, px, py, pz));
}
DEV float wgt(float d2) { return __builtin_amdgcn_rcpf(fmaxf(d2, 1e-16f)); }

// ---- bitonic helpers (verified R11/R14): compile-time indices only
template<int N>
DEV void bitonic_sort(u32 v[N]) {           // full ascending sort
    #pragma unroll
    for (int k = 2; k <= N; k <<= 1) {
        #pragma unroll
        for (int j = k >> 1; j > 0; j >>= 1) {
            #pragma unroll
            for (int i = 0; i < N; ++i) {
                const int l = i ^ j;
                if (l > i) {
                    const u32 lo = umin_(v[i], v[l]);
                    const u32 hi = umax_(v[i], v[l]);
                    const bool up = ((i & k) == 0);
                    v[i] = up ? lo : hi;
                    v[l] = up ? hi : lo;
                }
            }
        }
    }
}
template<int N>
DEV void bitonic_cleanup(u32 v[N]) {        // sort a bitonic sequence ascending
    #pragma unroll
    for (int j = N >> 1; j > 0; j >>= 1) {
        #pragma unroll
        for (int i = 0; i < N; ++i) {
            const int l = i ^ j;
            if (l > i) {
                const u32 lo = umin_(v[i], v[l]);
                v[l] = umax_(v[i], v[l]);
                v[i] = lo;
            }
        }
    }
}

// ============ selection kernel: TPT threads per target (R14, proven) =======
template<int K, int NSRC, int LOG_TPG, int TPT, int NT>
__global__ __launch_bounds__(NT) void knn_select(
    const float* __restrict__ pos_s, const float* __restrict__ pos_t,
    u32* __restrict__ Fout)
{
    constexpr int TPB = NT / TPT;
    constexpr int SL  = NSRC / TPT;
    constexpr int NB  = SL / K;
    constexpr int STRIDE = TPT * K + 1;
    __shared__ float4 sp[NSRC];
    __shared__ u32 lists[TPB * STRIDE];

    const int tid = threadIdx.x;
    const int w = tid / TPT, sub = tid % TPT;
    const int t = blockIdx.x * TPB + w;
    const int g = t >> LOG_TPG, sbase = g * NSRC;

    for (int i = tid; i < NSRC; i += NT) {
        const float* p = pos_s + (size_t)(sbase + i) * 3;
        const float px = p[0], py = p[1], pz = p[2];
        sp[i] = make_float4(px, py, pz, pnorm2(px, py, pz));
    }
    __syncthreads();

    const float qx = pos_t[t*3+0], qy = pos_t[t*3+1], qz = pos_t[t*3+2];
    const float qq = pnorm2(qx, qy, qz);

    u32 r[K];
    #pragma unroll
    for (int j = 0; j < K; ++j) r[j] = 0xFFFFFFFFu;

    for (int b = 0; b < NB; ++b) {
        u32 c[K];
        #pragma unroll
        for (int j = 0; j < K; ++j) {
            const float4 p = sp[(b * K + j) * TPT + sub];   // interleaved
            c[j] = fmap(dist2_core(qq, p.w, qdot(qx, qy, qz, p.x, p.y, p.z)));
        }
        bitonic_sort<K>(c);
        u32 m[K];
        #pragma unroll
        for (int i = 0; i < K; ++i) m[i] = umin_(r[i], c[K-1-i]);
        bitonic_cleanup<K>(m);
        #pragma unroll
        for (int i = 0; i < K; ++i) r[i] = m[i];
    }

    u32* Lw = lists + w * STRIDE;
    #pragma unroll
    for (int j = 0; j < K; ++j) Lw[sub * K + j] = r[j];
    __syncthreads();

    if (sub == 0) {
        u32 h[TPT]; int idx[TPT];
        #pragma unroll
        for (int l = 0; l < TPT; ++l) { h[l] = Lw[l*K]; idx[l] = 1; }
        u32 F = 0;
        #pragma unroll
        for (int step = 0; step < K; ++step) {
            u32 m = h[0];
            #pragma unroll
            for (int l = 1; l < TPT; ++l) m = umin_(m, h[l]);
            F = m;
            if (step < K - 1) {
                bool done = false;
                #pragma unroll
                for (int l = 0; l < TPT; ++l) {
                    if (!done && h[l] == m) {
                        h[l] = (idx[l] < K) ? Lw[l*K + idx[l]] : 0xFFFFFFFFu;
                        ++idx[l];
                        done = true;
                    }
                }
            }
        }
        Fout[t] = F;
    }
}

// ============ gather extraction: guarded LE sweep (R22, proven) ============
// Fast path: single LE sweep. If |LE| == K the LE set IS the top_k set.
// |LE| > K (float collision at F, rare, wave-uniform) -> exact two-sweep
// repair with lowest-index-first tie placement (R18 semantics).
template<int K, int M>
DEV void repair(const float fd[M], float Fd, int2* srw, int base,
                int sbase, int lane)
{
    int bl2 = 0, bt = 0; int tr[M];
    #pragma unroll
    for (int m = 0; m < M; ++m) {
        const u64 mlm = __ballot(fd[m] < Fd);
        const u64 mtm = __ballot(fd[m] == Fd);
        if (fd[m] < Fd) {
            const int slot = bl2 + lane_rank(mlm);
            srw[base + slot] = make_int2(__float_as_int(wgt(fd[m])),
                                         sbase + lane + m*64);
        }
        tr[m] = bt + lane_rank(mtm);
        bl2 += (int)__popcll(mlm);
        bt += (int)__popcll(mtm);
    }
    const int nless = bl2, need = K - nless;
    const float wtie = wgt(Fd);
    #pragma unroll
    for (int m = 0; m < M; ++m) {
        if (fd[m] == Fd && tr[m] < need) {
            srw[base + nless + tr[m]] = make_int2(__float_as_int(wtie),
                                                  sbase + lane + m*64);
        }
    }
}
template<int K, int M>
DEV void extract(const float fd[M], float Fd, int2* srw, int base,
                 int sbase, int lane)
{
    int bl = 0;
    #pragma unroll
    for (int m = 0; m < M; ++m) {
        const u64 mle = __ballot(fd[m] <= Fd);
        if (fd[m] <= Fd) {
            const int slot = bl + lane_rank(mle);
            if (slot < K)
                srw[base + slot] = make_int2(__float_as_int(wgt(fd[m])),
                                             sbase + lane + m*64);
        }
        bl += (int)__popcll(mle);
    }
    if (bl > K) repair<K, M>(fd, Fd, srw, base, sbase, lane);
}

// level 1: k=16, 1024 src/graph, C=64, concat 3 -> out [65536,67]
// 2 targets per wave: shared sp reads, dual independent sweep chains (ILP).
__global__ __launch_bounds__(512) void knn1_gather(
    const float* __restrict__ xsrc, const float* __restrict__ pos_s,
    const float* __restrict__ pos_t, const float* __restrict__ x_skip,
    const u32* __restrict__ Fbuf, float* __restrict__ out)
{
    constexpr int K = 16, M = 16;
    __shared__ float4 sp[1024];
    __shared__ int2 srw[16 * K];      // 8 waves x 2 targets
    const int lane = threadIdx.x & 63;
    const int wv = threadIdx.x >> 6;
    const int t0 = blockIdx.x * 16 + wv * 2;
    const int g = (blockIdx.x * 16) >> 12;      // uniform per block
    const int sbase = g << 10;

    for (int i = threadIdx.x; i < 1024; i += 512) {
        const float* p = pos_s + (size_t)(sbase + i) * 3;
        const float px = p[0], py = p[1], pz = p[2];
        sp[i] = make_float4(px, py, pz, pnorm2(px, py, pz));
    }
    __syncthreads();

    float qx[2], qy[2], qz[2], qq[2];
    #pragma unroll
    for (int i = 0; i < 2; ++i) {
        qx[i] = pos_t[(t0+i)*3+0];
        qy[i] = pos_t[(t0+i)*3+1];
        qz[i] = pos_t[(t0+i)*3+2];
        qq[i] = pnorm2(qx[i], qy[i], qz[i]);
    }
    float fd[2][M];
    #pragma unroll
    for (int m = 0; m < M; ++m) {
        const float4 p = sp[lane + m*64];
        #pragma unroll
        for (int i = 0; i < 2; ++i)
            fd[i][m] = dist2_core(qq[i], p.w,
                                  qdot(qx[i], qy[i], qz[i], p.x, p.y, p.z));
    }
    const float Fd0 = funmap(Fbuf[t0]);
    const float Fd1 = funmap(Fbuf[t0+1]);
    const int base0 = wv * 2 * K, base1 = base0 + K;

    // interleaved guarded LE sweeps: two independent chains
    int bl0 = 0, bl1 = 0;
    #pragma unroll
    for (int m = 0; m < M; ++m) {
        const u64 mle0 = __ballot(fd[0][m] <= Fd0);
        const u64 mle1 = __ballot(fd[1][m] <= Fd1);
        if (fd[0][m] <= Fd0) {
            const int slot = bl0 + lane_rank(mle0);
            if (slot < K)
                srw[base0 + slot] = make_int2(__float_as_int(wgt(fd[0][m])),
                                              sbase + lane + m*64);
        }
        if (fd[1][m] <= Fd1) {
            const int slot = bl1 + lane_rank(mle1);
            if (slot < K)
                srw[base1 + slot] = make_int2(__float_as_int(wgt(fd[1][m])),
                                              sbase + lane + m*64);
        }
        bl0 += (int)__popcll(mle0);
        bl1 += (int)__popcll(mle1);
    }
    if (bl0 > K) repair<K, M>(fd[0], Fd0, srw, base0, sbase, lane);
    if (bl1 > K) repair<K, M>(fd[1], Fd1, srw, base1, sbase, lane);
    __syncthreads();

    // pipelined gather: 2 x 16 independent loads
    #pragma unroll
    for (int i = 0; i < 2; ++i) {
        const int base = base0 + i * K;
        const int t = t0 + i;
        float wsum = 0.f, y = 0.f;
        #pragma unroll
        for (int j = 0; j < K; ++j) {
            const int2 rw = srw[base + j];
            const float w = __int_as_float(rw.x);
            wsum += w;
            y += w * xsrc[(size_t)rw.y * 64 + lane];
        }
        out[t*67 + lane] = y * (1.f / wsum);
        if (lane < 3) out[t*67 + 64 + lane] = x_skip[t*3 + lane];
    }
}

// level 2: k=8, 256 src/graph, C=128, concat 64 -> out [16384,192]
__global__ __launch_bounds__(512) void knn2_gather(
    const float* __restrict__ xsrc, const float* __restrict__ pos_s,
    const float* __restrict__ pos_t, const float* __restrict__ x_skip,
    const u32* __restrict__ Fbuf, float* __restrict__ out)
{
    constexpr int K = 8, M = 4;
    __shared__ float4 sp[256];
    __shared__ int2 srw[8 * K];
    const int lane = threadIdx.x & 63;
    const int wv = threadIdx.x >> 6;
    const int t = blockIdx.x * 8 + wv;
    const int g = (blockIdx.x * 8) >> 10;       // uniform per block
    const int sbase = g << 8;

    if (threadIdx.x < 256) {
        const int i = threadIdx.x;
        const float* p = pos_s + (size_t)(sbase + i) * 3;
        const float px = p[0], py = p[1], pz = p[2];
        sp[i] = make_float4(px, py, pz, pnorm2(px, py, pz));
    }
    __syncthreads();

    const float qx = pos_t[t*3+0], qy = pos_t[t*3+1], qz = pos_t[t*3+2];
    const float qq = pnorm2(qx, qy, qz);
    float fd[M];
    #pragma unroll
    for (int m = 0; m < M; ++m) {
        const float4 p = sp[lane + m*64];
        fd[m] = dist2_core(qq, p.w, qdot(qx, qy, qz, p.x, p.y, p.z));
    }
    const float Fd = funmap(Fbuf[t]);
    const int base = wv * K;

    extract<K, M>(fd, Fd, srw, base, sbase, lane);
    __syncthreads();

    float wsum = 0.f, y0 = 0.f, y1 = 0.f;
    #pragma unroll
    for (int j = 0; j < K; ++j) {
        const int2 rw = srw[base + j];
        const float w = __int_as_float(rw.x);
        const float* xr = xsrc + (size_t)rw.y * 128;
        wsum += w;
        y0 += w * xr[lane];
        y1 += w * xr[lane + 64];
    }
    const float inv = 1.f / wsum;
    out[t*192 + lane]      = y0 * inv;
    out[t*192 + lane + 64] = y1 * inv;
    out[t*192 + 128 + lane] = x_skip[t*64 + lane];
}

// ---------------- level 3: k=4, 64 src/graph, C=256 -> out [4096,384]
DEV u64 umin64(u64 a, u64 b) { return a < b ? a : b; }
DEV u64 shfl_xor_u64(u64 k, int off) {
    u32 lo = (u32)k, hi = (u32)(k >> 32);
    lo = (u32)__shfl_xor((int)lo, off, 64);
    hi = (u32)__shfl_xor((int)hi, off, 64);
    return ((u64)hi << 32) | lo;
}
DEV u64 wave_min_u64(u64 v) {
    #pragma unroll
    for (int off = 32; off; off >>= 1)
        v = umin64(v, shfl_xor_u64(v, off));
    return v;
}
DEV u64 make_key(float d2, int idx) { return ((u64)fmap(d2) << 10) | (u32)idx; }
DEV float key_weight(u64 k) {
    return __builtin_amdgcn_rcpf(fmaxf(funmap((u32)(k >> 10)), 1e-16f));
}
DEV int key_row(u64 k) {
    return __builtin_amdgcn_readfirstlane((int)((u32)k & 1023u));
}
#define KMAX 0xFFFFFFFFFFFFFFFFull

__global__ __launch_bounds__(256) void knn3_kernel(
    const float* __restrict__ x, const float* __restrict__ pos_s,
    const float* __restrict__ pos_t, const float* __restrict__ x_skip,
    float* __restrict__ out)
{
    const int lane = threadIdx.x & 63;
    const int t = blockIdx.x * 4 + (threadIdx.x >> 6);
    const int g = t >> 8, sbase = g << 6;
    const float qx = pos_t[t*3+0], qy = pos_t[t*3+1], qz = pos_t[t*3+2];
    const float qq = pnorm2(qx, qy, qz);
    const int s = sbase + lane;
    const u64 key = make_key(dist2(qx, qy, qz, qq,
                                   pos_s[s*3+0], pos_s[s*3+1], pos_s[s*3+2]), lane);

    float w[4]; int row[4]; float wsum = 0.f;
    u64 gprev = 0;
    #pragma unroll
    for (int j = 0; j < 4; ++j) {
        gprev = wave_min_u64(key > gprev ? key : KMAX);
        w[j] = key_weight(gprev);
        row[j] = sbase + key_row(gprev);
        wsum += w[j];
    }
    const float inv = 1.f / wsum;
    float y0 = 0.f, y1 = 0.f, y2 = 0.f, y3 = 0.f;
    #pragma unroll
    for (int j = 0; j < 4; ++j) {
        const float* xr = x + (size_t)row[j] * 256;
        y0 += w[j] * xr[lane];
        y1 += w[j] * xr[lane + 64];
        y2 += w[j] * xr[lane + 128];
        y3 += w[j] * xr[lane + 192];
    }
    out[t*384 + lane]       = y0 * inv;
    out[t*384 + lane + 64]  = y1 * inv;
    out[t*384 + lane + 128] = y2 * inv;
    out[t*384 + lane + 192] = y3 * inv;
    out[t*384 + 256 + lane]      = x_skip[t*128 + lane];
    out[t*384 + 256 + 64 + lane] = x_skip[t*128 + 64 + lane];
}

// ---------------- fused 2-layer MLP, G groups per block ---------------------
template<int K1, int C1, int C2, int ROWS, int G>
__global__ __launch_bounds__(C1 * G) void mlp2_kernel(
    const float* __restrict__ in, const float* __restrict__ Wa,
    const float* __restrict__ ba, const float* __restrict__ Wb,
    const float* __restrict__ bb, float* __restrict__ out, int N)
{
    __shared__ float xt[G][ROWS * K1];
    __shared__ float h1[G][ROWS * C1];
    const int tid = threadIdx.x % C1;
    const int gr  = threadIdx.x / C1;
    const int row0 = (blockIdx.x * G + gr) * ROWS;

    for (int f = tid; f < ROWS * K1; f += C1)
        xt[gr][f] = in[row0 * K1 + f];
    __syncthreads();

    float acc[ROWS];
    #pragma unroll
    for (int r = 0; r < ROWS; ++r) acc[r] = ba[tid];
    for (int k = 0; k < K1; ++k) {
        const float wv = Wa[tid * K1 + k];
        #pragma unroll
        for (int r = 0; r < ROWS; ++r) acc[r] += xt[gr][r * K1 + k] * wv;
    }
    #pragma unroll
    for (int r = 0; r < ROWS; ++r) h1[gr][r * C1 + tid] = tanhf(acc[r]);
    __syncthreads();

    if (tid < C2) {
        float acc2[ROWS];
        #pragma unroll
        for (int r = 0; r < ROWS; ++r) acc2[r] = bb[tid];
        for (int k = 0; k < C1; ++k) {
            const float wv = Wb[tid * C1 + k];
            #pragma unroll
            for (int r = 0; r < ROWS; ++r) acc2[r] += h1[gr][r * C1 + k] * wv;
        }
        #pragma unroll
        for (int r = 0; r < ROWS; ++r) out[(row0 + r) * C2 + tid] = acc2[r];
    }
}

// ---------------- final 3-layer MLP: xt/h2 LDS union (R22, proven) ---------
template<int ROWS>
__global__ __launch_bounds__(256) void mlp_final_kernel(
    const float* __restrict__ in,
    const float* __restrict__ Wa, const float* __restrict__ ba,
    const float* __restrict__ Wb, const float* __restrict__ bb,
    const float* __restrict__ Wc, const float* __restrict__ bc,
    float* __restrict__ out, int N)
{
    constexpr int K1 = 67, C = 64;
    __shared__ float smem[4][ROWS * K1 + ROWS * C];   // 536 + 512 per group
    const int tid = threadIdx.x & 63;
    const int wv = threadIdx.x >> 6;
    const int row0 = (blockIdx.x * 4 + wv) * ROWS;
    float* xt = smem[wv];                 // ROWS*K1, dead after layer 1
    float* h1 = smem[wv] + ROWS * K1;     // ROWS*C
    float* h2 = smem[wv];                 // ROWS*65 (520 <= 536), reuses xt

    for (int f = tid; f < ROWS * K1; f += C)
        xt[f] = in[row0 * K1 + f];
    __syncthreads();

    float acc[ROWS];
    #pragma unroll
    for (int r = 0; r < ROWS; ++r) acc[r] = ba[tid];
    for (int k = 0; k < K1; ++k) {
        const float wvv = Wa[tid * K1 + k];
        #pragma unroll
        for (int r = 0; r < ROWS; ++r) acc[r] += xt[r * K1 + k] * wvv;
    }
    #pragma unroll
    for (int r = 0; r < ROWS; ++r) h1[r * C + tid] = tanhf(acc[r]);
    __syncthreads();   // layer-1 done: xt region free

    float acc2[ROWS];
    #pragma unroll
    for (int r = 0; r < ROWS; ++r) acc2[r] = bb[tid];
    for (int k = 0; k < C; ++k) {
        const float wvv = Wb[tid * C + k];
        #pragma unroll
        for (int r = 0; r < ROWS; ++r) acc2[r] += h1[r * C + k] * wvv;
    }
    #pragma unroll
    for (int r = 0; r < ROWS; ++r) h2[r * 65 + tid] = tanhf(acc2[r]);
    __syncthreads();

    if (tid < ROWS * 3) {
        const int r = tid / 3, o = tid - r * 3;
        float a = bc[o];
        for (int k = 0; k < C; ++k) a += h2[r * 65 + k] * Wc[o * C + k];
        out[(row0 + r) * 3 + o] = a;
    }
}

extern "C" void kernel_launch(void* const* d_in, const int* in_sizes, int n_in,
                              void* d_out, int out_size, void* d_ws, size_t ws_size,
                              hipStream_t stream)
{
    const float* x       = (const float*)d_in[0];
    const float* pos     = (const float*)d_in[1];
    const float* x_skip2 = (const float*)d_in[3];
    const float* pos2    = (const float*)d_in[4];
    const float* x_skip1 = (const float*)d_in[6];
    const float* pos1    = (const float*)d_in[7];
    const float* x_skip0 = (const float*)d_in[9];
    const float* pos0    = (const float*)d_in[10];
    const float* W3a = (const float*)d_in[12]; const float* b3a = (const float*)d_in[13];
    const float* W3b = (const float*)d_in[14]; const float* b3b = (const float*)d_in[15];
    const float* W2a = (const float*)d_in[16]; const float* b2a = (const float*)d_in[17];
    const float* W2b = (const float*)d_in[18]; const float* b2b = (const float*)d_in[19];
    const float* W1a = (const float*)d_in[20]; const float* b1a = (const float*)d_in[21];
    const float* W1b = (const float*)d_in[22]; const float* b1b = (const float*)d_in[23];
    const float* W1c = (const float*)d_in[24]; const float* b1c = (const float*)d_in[25];

    float* buf1 = (float*)d_ws;                        // 65536*67 floats
    float* buf2 = buf1 + (size_t)65536 * 67;           // 16384*64 floats
    u32*   F1   = (u32*)(buf2 + (size_t)16384 * 64);   // 65536 u32
    u32*   F2   = F1 + 65536;                          // 16384 u32

    // level 3
    knn3_kernel<<<1024, 256, 0, stream>>>(x, pos, pos2, x_skip2, buf1);
    mlp2_kernel<384,128,128,8,2><<<4096/16, 256, 0, stream>>>(buf1, W3a, b3a, W3b, b3b, buf2, 4096);
    // level 2: select + gather (guarded LE sweep)
    knn_select<8, 256, 10, 4, 256><<<16384/64, 256, 0, stream>>>(pos2, pos1, F2);
    knn2_gather<<<16384/8, 512, 0, stream>>>(buf2, pos2, pos1, x_skip1, F2, buf1);
    mlp2_kernel<192,64,64,8,4><<<16384/32, 256, 0, stream>>>(buf1, W2a, b2a, W2b, b2b, buf2, 16384);
    // level 1: select + gather (2 targets/wave, guarded LE sweep)
    knn_select<16, 1024, 12, 4, 512><<<65536/128, 512, 0, stream>>>(pos1, pos0, F1);
    knn1_gather<<<65536/16, 512, 0, stream>>>(buf2, pos1, pos0, x_skip0, F1, buf1);
    mlp_final_kernel<8><<<65536/32, 256, 0, stream>>>(buf1, W1a, b1a, W1b, b1b, W1c, b1c,
                                                      (float*)d_out, 65536);
}

// Round 25
// 200.599 us; speedup vs baseline: 1.0239x; 1.0239x over previous
//
#include <hip/hip_runtime.h>
#include <math.h>

#define DEV __device__ __forceinline__

typedef unsigned long long u64;
typedef unsigned u32;

// monotone map: float bits -> u32 preserving < order (handles negatives)
DEV u32 fmap(float f) {
    u32 b = __float_as_uint(f);
    return b ^ (u32)(((int)b >> 31) | 0x80000000);
}
// exact inverse of fmap
DEV float funmap(u32 m) {
    u32 b = (m & 0x80000000u) ? (m ^ 0x80000000u) : ~m;
    return __uint_as_float(b);
}
DEV u32 umin_(u32 a, u32 b) { return __builtin_elementwise_min(a, b); }
DEV u32 umax_(u32 a, u32 b) { return __builtin_elementwise_max(a, b); }

// rank among lanes below me with bit set: popcll(mask & lanemask_lt), 2 VALU
DEV int lane_rank(u64 mask) {
    return (int)__builtin_amdgcn_mbcnt_hi((u32)(mask >> 32),
               __builtin_amdgcn_mbcnt_lo((u32)mask, 0u));
}

// ---- BIT-EXACT distance pieces: explicit _rn intrinsics, composed the same
// way in every kernel. R16-proven rounding (absmax 0.00390625) — do not fold.
DEV float pnorm2(float x, float y, float z) {
    return __fmaf_rn(x, x, __fmaf_rn(y, y, __fmul_rn(z, z)));
}
DEV float qdot(float qx, float qy, float qz, float px, float py, float pz) {
    return __fmaf_rn(qx, px, __fmaf_rn(qy, py, __fmul_rn(qz, pz)));
}
DEV float dist2_core(float qq, float pp, float qp) {
    return __fadd_rn(__fadd_rn(qq, pp), __fmul_rn(-2.f, qp));
}
DEV float dist2(float qx, float qy, float qz, float qq,
                float px, float py, float pz) {
    return dist2_core(qq, pnorm2(px, py, pz), qdot(qx, qy, qz, px, py, pz));
}
DEV float wgt(float d2) { return __builtin_amdgcn_rcpf(fmaxf(d2, 1e-16f)); }

// ---- bitonic helpers (verified R11/R14): compile-time indices only
template<int N>
DEV void bitonic_sort(u32 v[N]) {           // full ascending sort
    #pragma unroll
    for (int k = 2; k <= N; k <<= 1) {
        #pragma unroll
        for (int j = k >> 1; j > 0; j >>= 1) {
            #pragma unroll
            for (int i = 0; i < N; ++i) {
                const int l = i ^ j;
                if (l > i) {
                    const u32 lo = umin_(v[i], v[l]);
                    const u32 hi = umax_(v[i], v[l]);
                    const bool up = ((i & k) == 0);
                    v[i] = up ? lo : hi;
                    v[l] = up ? hi : lo;
                }
            }
        }
    }
}
template<int N>
DEV void bitonic_cleanup(u32 v[N]) {        // sort a bitonic sequence ascending
    #pragma unroll
    for (int j = N >> 1; j > 0; j >>= 1) {
        #pragma unroll
        for (int i = 0; i < N; ++i) {
            const int l = i ^ j;
            if (l > i) {
                const u32 lo = umin_(v[i], v[l]);
                v[l] = umax_(v[i], v[l]);
                v[i] = lo;
            }
        }
    }
}

// ============ selection kernel: TPT threads per target (R14, proven) =======
template<int K, int NSRC, int LOG_TPG, int TPT, int NT>
__global__ __launch_bounds__(NT) void knn_select(
    const float* __restrict__ pos_s, const float* __restrict__ pos_t,
    u32* __restrict__ Fout)
{
    constexpr int TPB = NT / TPT;
    constexpr int SL  = NSRC / TPT;
    constexpr int NB  = SL / K;
    constexpr int STRIDE = TPT * K + 1;
    __shared__ float4 sp[NSRC];
    __shared__ u32 lists[TPB * STRIDE];

    const int tid = threadIdx.x;
    const int w = tid / TPT, sub = tid % TPT;
    const int t = blockIdx.x * TPB + w;
    const int g = t >> LOG_TPG, sbase = g * NSRC;

    for (int i = tid; i < NSRC; i += NT) {
        const float* p = pos_s + (size_t)(sbase + i) * 3;
        const float px = p[0], py = p[1], pz = p[2];
        sp[i] = make_float4(px, py, pz, pnorm2(px, py, pz));
    }
    __syncthreads();

    const float qx = pos_t[t*3+0], qy = pos_t[t*3+1], qz = pos_t[t*3+2];
    const float qq = pnorm2(qx, qy, qz);

    u32 r[K];
    #pragma unroll
    for (int j = 0; j < K; ++j) r[j] = 0xFFFFFFFFu;

    for (int b = 0; b < NB; ++b) {
        u32 c[K];
        #pragma unroll
        for (int j = 0; j < K; ++j) {
            const float4 p = sp[(b * K + j) * TPT + sub];   // interleaved
            c[j] = fmap(dist2_core(qq, p.w, qdot(qx, qy, qz, p.x, p.y, p.z)));
        }
        bitonic_sort<K>(c);
        u32 m[K];
        #pragma unroll
        for (int i = 0; i < K; ++i) m[i] = umin_(r[i], c[K-1-i]);
        bitonic_cleanup<K>(m);
        #pragma unroll
        for (int i = 0; i < K; ++i) r[i] = m[i];
    }

    u32* Lw = lists + w * STRIDE;
    #pragma unroll
    for (int j = 0; j < K; ++j) Lw[sub * K + j] = r[j];
    __syncthreads();

    if (sub == 0) {
        u32 h[TPT]; int idx[TPT];
        #pragma unroll
        for (int l = 0; l < TPT; ++l) { h[l] = Lw[l*K]; idx[l] = 1; }
        u32 F = 0;
        #pragma unroll
        for (int step = 0; step < K; ++step) {
            u32 m = h[0];
            #pragma unroll
            for (int l = 1; l < TPT; ++l) m = umin_(m, h[l]);
            F = m;
            if (step < K - 1) {
                bool done = false;
                #pragma unroll
                for (int l = 0; l < TPT; ++l) {
                    if (!done && h[l] == m) {
                        h[l] = (idx[l] < K) ? Lw[l*K + idx[l]] : 0xFFFFFFFFu;
                        ++idx[l];
                        done = true;
                    }
                }
            }
        }
        Fout[t] = F;
    }
}

// ============ gather extraction: guarded LE sweep ==========================
// Fast path: single LE sweep. If |LE| == K the LE set IS the top_k set.
// |LE| > K (float collision at F, rare, wave-uniform) -> exact two-sweep
// repair with lowest-index-first tie placement (R18 semantics).
template<int K, int M>
DEV void extract(const float fd[M], float Fd, int2* srw, int base,
                 int sbase, int lane)
{
    int bl = 0;
    #pragma unroll
    for (int m = 0; m < M; ++m) {
        const u64 mle = __ballot(fd[m] <= Fd);
        if (fd[m] <= Fd) {
            const int slot = bl + lane_rank(mle);
            if (slot < K)
                srw[base + slot] = make_int2(__float_as_int(wgt(fd[m])),
                                             sbase + lane + m*64);
        }
        bl += (int)__popcll(mle);
    }
    if (bl > K) {   // wave-uniform rare repair: exact two-sweep
        int bl2 = 0, bt = 0; int tr[M];
        #pragma unroll
        for (int m = 0; m < M; ++m) {
            const u64 mlm = __ballot(fd[m] < Fd);
            const u64 mtm = __ballot(fd[m] == Fd);
            if (fd[m] < Fd) {
                const int slot = bl2 + lane_rank(mlm);
                srw[base + slot] = make_int2(__float_as_int(wgt(fd[m])),
                                             sbase + lane + m*64);
            }
            tr[m] = bt + lane_rank(mtm);
            bl2 += (int)__popcll(mlm);
            bt += (int)__popcll(mtm);
        }
        const int nless = bl2, need = K - nless;
        const float wtie = wgt(Fd);
        #pragma unroll
        for (int m = 0; m < M; ++m) {
            if (fd[m] == Fd && tr[m] < need) {
                srw[base + nless + tr[m]] = make_int2(__float_as_int(wtie),
                                                      sbase + lane + m*64);
            }
        }
    }
}

// level 1: k=16, 1024 src/graph, C=64, concat 3 -> out [65536,67]
__global__ __launch_bounds__(512) void knn1_gather(
    const float* __restrict__ xsrc, const float* __restrict__ pos_s,
    const float* __restrict__ pos_t, const float* __restrict__ x_skip,
    const u32* __restrict__ Fbuf, float* __restrict__ out)
{
    constexpr int K = 16, M = 16;
    __shared__ float4 sp[1024];
    __shared__ int2 srw[8 * K];       // .x = w bits, .y = row
    const int lane = threadIdx.x & 63;
    const int wv = threadIdx.x >> 6;
    const int t = blockIdx.x * 8 + wv;
    const int g = (blockIdx.x * 8) >> 12;       // uniform per block
    const int sbase = g << 10;

    for (int i = threadIdx.x; i < 1024; i += 512) {
        const float* p = pos_s + (size_t)(sbase + i) * 3;
        const float px = p[0], py = p[1], pz = p[2];
        sp[i] = make_float4(px, py, pz, pnorm2(px, py, pz));
    }
    __syncthreads();

    const float qx = pos_t[t*3+0], qy = pos_t[t*3+1], qz = pos_t[t*3+2];
    const float qq = pnorm2(qx, qy, qz);
    float fd[M];
    #pragma unroll
    for (int m = 0; m < M; ++m) {
        const float4 p = sp[lane + m*64];
        fd[m] = dist2_core(qq, p.w, qdot(qx, qy, qz, p.x, p.y, p.z));
    }
    const float Fd = funmap(Fbuf[t]);
    const int base = wv * K;

    extract<K, M>(fd, Fd, srw, base, sbase, lane);
    __syncthreads();

    // pipelined gather: 16 independent loads
    float wsum = 0.f, y = 0.f;
    #pragma unroll
    for (int j = 0; j < K; ++j) {
        const int2 rw = srw[base + j];
        const float w = __int_as_float(rw.x);
        wsum += w;
        y += w * xsrc[(size_t)rw.y * 64 + lane];
    }
    out[t*67 + lane] = y * (1.f / wsum);
    if (lane < 3) out[t*67 + 64 + lane] = x_skip[t*3 + lane];
}

// level 2: k=8, 256 src/graph, C=128, concat 64 -> out [16384,192]
__global__ __launch_bounds__(512) void knn2_gather(
    const float* __restrict__ xsrc, const float* __restrict__ pos_s,
    const float* __restrict__ pos_t, const float* __restrict__ x_skip,
    const u32* __restrict__ Fbuf, float* __restrict__ out)
{
    constexpr int K = 8, M = 4;
    __shared__ float4 sp[256];
    __shared__ int2 srw[8 * K];
    const int lane = threadIdx.x & 63;
    const int wv = threadIdx.x >> 6;
    const int t = blockIdx.x * 8 + wv;
    const int g = (blockIdx.x * 8) >> 10;       // uniform per block
    const int sbase = g << 8;

    if (threadIdx.x < 256) {
        const int i = threadIdx.x;
        const float* p = pos_s + (size_t)(sbase + i) * 3;
        const float px = p[0], py = p[1], pz = p[2];
        sp[i] = make_float4(px, py, pz, pnorm2(px, py, pz));
    }
    __syncthreads();

    const float qx = pos_t[t*3+0], qy = pos_t[t*3+1], qz = pos_t[t*3+2];
    const float qq = pnorm2(qx, qy, qz);
    float fd[M];
    #pragma unroll
    for (int m = 0; m < M; ++m) {
        const float4 p = sp[lane + m*64];
        fd[m] = dist2_core(qq, p.w, qdot(qx, qy, qz, p.x, p.y, p.z));
    }
    const float Fd = funmap(Fbuf[t]);
    const int base = wv * K;

    extract<K, M>(fd, Fd, srw, base, sbase, lane);
    __syncthreads();

    float wsum = 0.f, y0 = 0.f, y1 = 0.f;
    #pragma unroll
    for (int j = 0; j < K; ++j) {
        const int2 rw = srw[base + j];
        const float w = __int_as_float(rw.x);
        const float* xr = xsrc + (size_t)rw.y * 128;
        wsum += w;
        y0 += w * xr[lane];
        y1 += w * xr[lane + 64];
    }
    const float inv = 1.f / wsum;
    out[t*192 + lane]      = y0 * inv;
    out[t*192 + lane + 64] = y1 * inv;
    out[t*192 + 128 + lane] = x_skip[t*64 + lane];
}

// ---------------- level 3: k=4, 64 src/graph, C=256 -> out [4096,384]
DEV u64 umin64(u64 a, u64 b) { return a < b ? a : b; }
DEV u64 shfl_xor_u64(u64 k, int off) {
    u32 lo = (u32)k, hi = (u32)(k >> 32);
    lo = (u32)__shfl_xor((int)lo, off, 64);
    hi = (u32)__shfl_xor((int)hi, off, 64);
    return ((u64)hi << 32) | lo;
}
DEV u64 wave_min_u64(u64 v) {
    #pragma unroll
    for (int off = 32; off; off >>= 1)
        v = umin64(v, shfl_xor_u64(v, off));
    return v;
}
DEV u64 make_key(float d2, int idx) { return ((u64)fmap(d2) << 10) | (u32)idx; }
DEV float key_weight(u64 k) {
    return __builtin_amdgcn_rcpf(fmaxf(funmap((u32)(k >> 10)), 1e-16f));
}
DEV int key_row(u64 k) {
    return __builtin_amdgcn_readfirstlane((int)((u32)k & 1023u));
}
#define KMAX 0xFFFFFFFFFFFFFFFFull

__global__ __launch_bounds__(256) void knn3_kernel(
    const float* __restrict__ x, const float* __restrict__ pos_s,
    const float* __restrict__ pos_t, const float* __restrict__ x_skip,
    float* __restrict__ out)
{
    const int lane = threadIdx.x & 63;
    const int t = blockIdx.x * 4 + (threadIdx.x >> 6);
    const int g = t >> 8, sbase = g << 6;
    const float qx = pos_t[t*3+0], qy = pos_t[t*3+1], qz = pos_t[t*3+2];
    const float qq = pnorm2(qx, qy, qz);
    const int s = sbase + lane;
    const u64 key = make_key(dist2(qx, qy, qz, qq,
                                   pos_s[s*3+0], pos_s[s*3+1], pos_s[s*3+2]), lane);

    float w[4]; int row[4]; float wsum = 0.f;
    u64 gprev = 0;
    #pragma unroll
    for (int j = 0; j < 4; ++j) {
        gprev = wave_min_u64(key > gprev ? key : KMAX);
        w[j] = key_weight(gprev);
        row[j] = sbase + key_row(gprev);
        wsum += w[j];
    }
    const float inv = 1.f / wsum;
    float y0 = 0.f, y1 = 0.f, y2 = 0.f, y3 = 0.f;
    #pragma unroll
    for (int j = 0; j < 4; ++j) {
        const float* xr = x + (size_t)row[j] * 256;
        y0 += w[j] * xr[lane];
        y1 += w[j] * xr[lane + 64];
        y2 += w[j] * xr[lane + 128];
        y3 += w[j] * xr[lane + 192];
    }
    out[t*384 + lane]       = y0 * inv;
    out[t*384 + lane + 64]  = y1 * inv;
    out[t*384 + lane + 128] = y2 * inv;
    out[t*384 + lane + 192] = y3 * inv;
    out[t*384 + 256 + lane]      = x_skip[t*128 + lane];
    out[t*384 + 256 + 64 + lane] = x_skip[t*128 + 64 + lane];
}

// ---------------- fused 2-layer MLP, G groups per block ---------------------
template<int K1, int C1, int C2, int ROWS, int G>
__global__ __launch_bounds__(C1 * G) void mlp2_kernel(
    const float* __restrict__ in, const float* __restrict__ Wa,
    const float* __restrict__ ba, const float* __restrict__ Wb,
    const float* __restrict__ bb, float* __restrict__ out, int N)
{
    __shared__ float xt[G][ROWS * K1];
    __shared__ float h1[G][ROWS * C1];
    const int tid = threadIdx.x % C1;
    const int gr  = threadIdx.x / C1;
    const int row0 = (blockIdx.x * G + gr) * ROWS;

    for (int f = tid; f < ROWS * K1; f += C1)
        xt[gr][f] = in[row0 * K1 + f];
    __syncthreads();

    float acc[ROWS];
    #pragma unroll
    for (int r = 0; r < ROWS; ++r) acc[r] = ba[tid];
    for (int k = 0; k < K1; ++k) {
        const float wv = Wa[tid * K1 + k];
        #pragma unroll
        for (int r = 0; r < ROWS; ++r) acc[r] += xt[gr][r * K1 + k] * wv;
    }
    #pragma unroll
    for (int r = 0; r < ROWS; ++r) h1[gr][r * C1 + tid] = tanhf(acc[r]);
    __syncthreads();

    if (tid < C2) {
        float acc2[ROWS];
        #pragma unroll
        for (int r = 0; r < ROWS; ++r) acc2[r] = bb[tid];
        for (int k = 0; k < C1; ++k) {
            const float wv = Wb[tid * C1 + k];
            #pragma unroll
            for (int r = 0; r < ROWS; ++r) acc2[r] += h1[gr][r * C1 + k] * wv;
        }
        #pragma unroll
        for (int r = 0; r < ROWS; ++r) out[(row0 + r) * C2 + tid] = acc2[r];
    }
}

// ---------------- final 3-layer MLP: xt/h2 LDS union (16.4 KB/block) -------
template<int ROWS>
__global__ __launch_bounds__(256) void mlp_final_kernel(
    const float* __restrict__ in,
    const float* __restrict__ Wa, const float* __restrict__ ba,
    const float* __restrict__ Wb, const float* __restrict__ bb,
    const float* __restrict__ Wc, const float* __restrict__ bc,
    float* __restrict__ out, int N)
{
    constexpr int K1 = 67, C = 64;
    __shared__ float smem[4][ROWS * K1 + ROWS * C];   // 536 + 512 per group
    const int tid = threadIdx.x & 63;
    const int wv = threadIdx.x >> 6;
    const int row0 = (blockIdx.x * 4 + wv) * ROWS;
    float* xt = smem[wv];                 // ROWS*K1, dead after layer 1
    float* h1 = smem[wv] + ROWS * K1;     // ROWS*C
    float* h2 = smem[wv];                 // ROWS*65 (520 <= 536), reuses xt

    for (int f = tid; f < ROWS * K1; f += C)
        xt[f] = in[row0 * K1 + f];
    __syncthreads();

    float acc[ROWS];
    #pragma unroll
    for (int r = 0; r < ROWS; ++r) acc[r] = ba[tid];
    for (int k = 0; k < K1; ++k) {
        const float wvv = Wa[tid * K1 + k];
        #pragma unroll
        for (int r = 0; r < ROWS; ++r) acc[r] += xt[r * K1 + k] * wvv;
    }
    #pragma unroll
    for (int r = 0; r < ROWS; ++r) h1[r * C + tid] = tanhf(acc[r]);
    __syncthreads();   // layer-1 done: xt region free

    float acc2[ROWS];
    #pragma unroll
    for (int r = 0; r < ROWS; ++r) acc2[r] = bb[tid];
    for (int k = 0; k < C; ++k) {
        const float wvv = Wb[tid * C + k];
        #pragma unroll
        for (int r = 0; r < ROWS; ++r) acc2[r] += h1[r * C + k] * wvv;
    }
    #pragma unroll
    for (int r = 0; r < ROWS; ++r) h2[r * 65 + tid] = tanhf(acc2[r]);
    __syncthreads();

    if (tid < ROWS * 3) {
        const int r = tid / 3, o = tid - r * 3;
        float a = bc[o];
        for (int k = 0; k < C; ++k) a += h2[r * 65 + k] * Wc[o * C + k];
        out[(row0 + r) * 3 + o] = a;
    }
}

extern "C" void kernel_launch(void* const* d_in, const int* in_sizes, int n_in,
                              void* d_out, int out_size, void* d_ws, size_t ws_size,
                              hipStream_t stream)
{
    const float* x       = (const float*)d_in[0];
    const float* pos     = (const float*)d_in[1];
    const float* x_skip2 = (const float*)d_in[3];
    const float* pos2    = (const float*)d_in[4];
    const float* x_skip1 = (const float*)d_in[6];
    const float* pos1    = (const float*)d_in[7];
    const float* x_skip0 = (const float*)d_in[9];
    const float* pos0    = (const float*)d_in[10];
    const float* W3a = (const float*)d_in[12]; const float* b3a = (const float*)d_in[13];
    const float* W3b = (const float*)d_in[14]; const float* b3b = (const float*)d_in[15];
    const float* W2a = (const float*)d_in[16]; const float* b2a = (const float*)d_in[17];
    const float* W2b = (const float*)d_in[18]; const float* b2b = (const float*)d_in[19];
    const float* W1a = (const float*)d_in[20]; const float* b1a = (const float*)d_in[21];
    const float* W1b = (const float*)d_in[22]; const float* b1b = (const float*)d_in[23];
    const float* W1c = (const float*)d_in[24]; const float* b1c = (const float*)d_in[25];

    float* buf1 = (float*)d_ws;                        // 65536*67 floats
    float* buf2 = buf1 + (size_t)65536 * 67;           // 16384*64 floats
    u32*   F1   = (u32*)(buf2 + (size_t)16384 * 64);   // 65536 u32
    u32*   F2   = F1 + 65536;                          // 16384 u32

    // level 3
    knn3_kernel<<<1024, 256, 0, stream>>>(x, pos, pos2, x_skip2, buf1);
    mlp2_kernel<384,128,128,8,2><<<4096/16, 256, 0, stream>>>(buf1, W3a, b3a, W3b, b3b, buf2, 4096);
    // level 2: select + gather (guarded LE sweep)
    knn_select<8, 256, 10, 4, 256><<<16384/64, 256, 0, stream>>>(pos2, pos1, F2);
    knn2_gather<<<16384/8, 512, 0, stream>>>(buf2, pos2, pos1, x_skip1, F2, buf1);
    mlp2_kernel<192,64,64,8,4><<<16384/32, 256, 0, stream>>>(buf1, W2a, b2a, W2b, b2b, buf2, 16384);
    // level 1: select + gather (guarded LE sweep)
    knn_select<16, 1024, 12, 4, 512><<<65536/128, 512, 0, stream>>>(pos1, pos0, F1);
    knn1_gather<<<65536/8, 512, 0, stream>>>(buf2, pos1, pos0, x_skip0, F1, buf1);
    mlp_final_kernel<8><<<65536/32, 256, 0, stream>>>(buf1, W1a, b1a, W1b, b1b, W1c, b1c,
                                                      (float*)d_out, 65536);
}